// Round 7
// baseline (957.292 us; speedup 1.0000x reference)
//
#include <hip/hip_runtime.h>

// B,T,D_IN,H,LAT = 256,512,32,128,64.
// R18 MULTI-SAMPLE: 16 blocks x 16 samples/block. MFMA B-columns = 16 REAL
// samples (was: 16x redundant broadcast of one h). Same 160 MFMA/step/block
// now serve 16 samples. A-rows ordered 4*unit+gate so lane's 4 C-regs =
// i,f,g,o of one (unit,sample): tail is pure per-lane scalar code, no DPP.
// h state [16][136] f16 in LDS (pad -> 2-way bank conflicts only). x loaded
// from global per step (prefetched; L2-resident). Decoder h-history streamed
// to d_ws; second kernel (256 blocks) does outD = hist @ dWl.T + dBl.
// Verified mappings reused: A row=l&15,k=8*(l>>4)+j (R0); B col=l&15
// (m89/m91 asymmetric GEMM verification); C col=l&15,row=4*(l>>4)+reg (m89).
#define NB   256
#define NT   512
#define NDIN 32
#define NH   128
#define NLAT 64
#define SPB  16      // samples per block
#define NBLK 16      // blocks
#define HR   136     // padded h row (f16): 272B -> bank-conflict-free-ish

typedef _Float16 f16x8 __attribute__((ext_vector_type(8)));
typedef float    f32x4 __attribute__((ext_vector_type(4)));
typedef _Float16 h2    __attribute__((ext_vector_type(2)));
typedef _Float16 h4    __attribute__((ext_vector_type(4)));

__device__ __forceinline__ float dot2(h2 a, h2 b, float c) {
  return __builtin_amdgcn_fdot2(a, b, c, false);
}
__device__ __forceinline__ h2 bc2(float v) { return __builtin_bit_cast(h2, v); }
__device__ __forceinline__ h2 pk2(float a, float b) { return h2{(_Float16)a, (_Float16)b}; }

#define NLOG2E 1.44269504f
__device__ __forceinline__ float sigmoid_f(float x) {
  return __builtin_amdgcn_rcpf(1.f + __builtin_amdgcn_exp2f(x * -NLOG2E));
}
__device__ __forceinline__ float tanh_f(float x) {
  float s = __builtin_amdgcn_rcpf(1.f + __builtin_amdgcn_exp2f(x * (-2.f * NLOG2E)));
  return fmaf(2.f, s, -1.f);
}
__device__ __forceinline__ f32x4 mfma16(f16x8 a, f16x8 b, f32x4 c) {
  return __builtin_amdgcn_mfma_f32_16x16x32_f16(a, b, c, 0, 0, 0);
}

// LDS: hs[2][16][136] f16 (8704B) | encs[16][64] f32 (4096B) | gtmp[16][512] f32 (32768B)
#define HS_BYTES   (2 * SPB * HR * 2)
#define ENC_BYTES  (SPB * NLAT * 4)
#define SMEM_MAIN  (HS_BYTES + ENC_BYTES + SPB * 512 * 4)

__global__ __launch_bounds__(512, 1) void lstm_ae_main(
    const float* __restrict__ x,      // [B][T][D_IN]
    const float* __restrict__ eWih,   // [4H][D_IN]
    const float* __restrict__ eWhh,   // [4H][H]
    const float* __restrict__ eBih,   // [4H]
    const float* __restrict__ eBhh,   // [4H]
    const float* __restrict__ eWl,    // [LAT][H]
    const float* __restrict__ eBl,    // [LAT]
    const float* __restrict__ dWih,   // [4H][LAT]
    const float* __restrict__ dWhh,   // [4H][H]
    const float* __restrict__ dBih,   // [4H]
    const float* __restrict__ dBhh,   // [4H]
    _Float16* __restrict__ hist,      // ws: [B][T][H] f16
    float* __restrict__ outE)         // [B][LAT]
{
  extern __shared__ __align__(16) char smem[];
  _Float16* hs   = (_Float16*)smem;                       // [2][16][136]
  float*    encs = (float*)(smem + HS_BYTES);             // [16][64]
  float*    gtmp = (float*)(smem + HS_BYTES + ENC_BYTES); // [16][512]

  const int tid = threadIdx.x;
  const int bid = blockIdx.x;
  const int w   = tid >> 6;       // wave 0..7
  const int l   = tid & 63;
  const int s   = l & 15;         // sample slot = A-row index = B/C column
  const int kg  = l >> 4;         // k-group 0..3
  const int ag  = s & 3;          // gate of this lane's A-row (row = 4u'+g)
  const int q   = s >> 2;         // unit-part of this lane's A-row
  const int ubase = 16 * w + 4 * kg;   // lane's acc units: ubase+tt
  const int S   = bid * SPB + s;  // global sample id

  // ---- encoder fragments ----
  // Tile tt of wave w: A-row r (=l&15) <-> unit = 16w + 4*(r>>2) + tt, gate = r&3.
  // C: lane holds col=s, rows 4*kg+j -> unit = ubase+tt, gate = j.
  f16x8 aw[4][4];   // [tile][K-block] Whh
  f16x8 axf[4];     // [tile]          Wih
  f32x4 bi[4];      // [tile]          per-gate bias C-init for (ubase+tt)
#pragma unroll
  for (int tt = 0; tt < 4; ++tt) {
    const int urow = 16 * w + 4 * q + tt;
    const float* rW = eWhh + (size_t)(ag * NH + urow) * NH;
#pragma unroll
    for (int K = 0; K < 4; ++K) {
      const float* p = rW + 32 * K + 8 * kg;
#pragma unroll
      for (int j = 0; j < 8; ++j) aw[tt][K][j] = (_Float16)p[j];
    }
    const float* rX = eWih + (size_t)(ag * NH + urow) * NDIN;
#pragma unroll
    for (int j = 0; j < 8; ++j) axf[tt][j] = (_Float16)rX[8 * kg + j];
#pragma unroll
    for (int j = 0; j < 4; ++j)
      bi[tt][j] = eBih[j * NH + ubase + tt] + eBhh[j * NH + ubase + tt];
  }
  // zero both h buffers (incl. pad)
  for (int i = tid; i < 2 * SPB * HR; i += 512) hs[i] = (_Float16)0.f;
  float c0 = 0.f, c1 = 0.f, c2 = 0.f, c3 = 0.f;

  // x prefetch for t=0 (global, per-lane: sample S, dims 8kg..8kg+7)
  const float* xb = x + (size_t)S * (NT * NDIN) + 8 * kg;
  float4 cxa = *(const float4*)(xb);
  float4 cxb = *(const float4*)(xb + 4);
  __syncthreads();

  // ============================ ENCODER ============================
#pragma unroll 1
  for (int t = 0; t < NT; ++t) {
    // build x fragment from prefetched regs
    f16x8 xf;
    xf[0] = (_Float16)cxa.x; xf[1] = (_Float16)cxa.y;
    xf[2] = (_Float16)cxa.z; xf[3] = (_Float16)cxa.w;
    xf[4] = (_Float16)cxb.x; xf[5] = (_Float16)cxb.y;
    xf[6] = (_Float16)cxb.z; xf[7] = (_Float16)cxb.w;
    // issue prefetch for t+1 early (hidden under MFMAs)
    int tn = (t + 1 < NT) ? (t + 1) : (NT - 1);
    float4 nxa = *(const float4*)(xb + (size_t)tn * NDIN);
    float4 nxb = *(const float4*)(xb + (size_t)tn * NDIN + 4);

    f32x4 acc[4];
#pragma unroll
    for (int tt = 0; tt < 4; ++tt) acc[tt] = mfma16(axf[tt], xf, bi[tt]);
    const _Float16* hb = hs + (t & 1) * (SPB * HR) + s * HR;
#pragma unroll
    for (int K = 0; K < 4; ++K) {
      f16x8 bf = *(const f16x8*)(hb + 32 * K + 8 * kg);
#pragma unroll
      for (int tt = 0; tt < 4; ++tt) acc[tt] = mfma16(aw[tt][K], bf, acc[tt]);
    }
    // tail: lane owns (unit ubase+tt, sample s); acc[tt] = {i,f,g,o}
    h4 hv;
    {
      float gi = sigmoid_f(acc[0][0]), gf = sigmoid_f(acc[0][1]);
      float gg = tanh_f(acc[0][2]),    go = sigmoid_f(acc[0][3]);
      c0 = fmaf(gf, c0, gi * gg); hv[0] = (_Float16)(go * tanh_f(c0));
    }
    {
      float gi = sigmoid_f(acc[1][0]), gf = sigmoid_f(acc[1][1]);
      float gg = tanh_f(acc[1][2]),    go = sigmoid_f(acc[1][3]);
      c1 = fmaf(gf, c1, gi * gg); hv[1] = (_Float16)(go * tanh_f(c1));
    }
    {
      float gi = sigmoid_f(acc[2][0]), gf = sigmoid_f(acc[2][1]);
      float gg = tanh_f(acc[2][2]),    go = sigmoid_f(acc[2][3]);
      c2 = fmaf(gf, c2, gi * gg); hv[2] = (_Float16)(go * tanh_f(c2));
    }
    {
      float gi = sigmoid_f(acc[3][0]), gf = sigmoid_f(acc[3][1]);
      float gg = tanh_f(acc[3][2]),    go = sigmoid_f(acc[3][3]);
      c3 = fmaf(gf, c3, gi * gg); hv[3] = (_Float16)(go * tanh_f(c3));
    }
    *(h4*)(hs + ((t + 1) & 1) * (SPB * HR) + s * HR + ubase) = hv;
    cxa = nxa; cxb = nxb;
    __syncthreads();
  }

  // ==================== LATENT (h_last in buffer 0) ====================
#pragma unroll
  for (int k = 0; k < 2; ++k) {
    int idx = tid + 512 * k;           // 1024 = 16 samples x 64 latents
    int ls = idx >> 6, lat = idx & 63;
    const float4* p  = (const float4*)(eWl + (size_t)lat * NH);
    const h2* hh = (const h2*)(hs + ls * HR);
    float a = eBl[lat];
#pragma unroll
    for (int r = 0; r < 32; ++r) {
      float4 wv = p[r];
      h2 e0 = hh[2 * r], e1 = hh[2 * r + 1];
      a = fmaf((float)e0.x, wv.x, a); a = fmaf((float)e0.y, wv.y, a);
      a = fmaf((float)e1.x, wv.z, a); a = fmaf((float)e1.y, wv.w, a);
    }
    encs[ls * NLAT + lat] = a;
    outE[(size_t)(bid * SPB + ls) * NLAT + lat] = a;
  }
  // decoder Whh fragments (same mapping; axf dead)
#pragma unroll
  for (int tt = 0; tt < 4; ++tt) {
    const int urow = 16 * w + 4 * q + tt;
    const float* rW = dWhh + (size_t)(ag * NH + urow) * NH;
#pragma unroll
    for (int K = 0; K < 4; ++K) {
      const float* p = rW + 32 * K + 8 * kg;
#pragma unroll
      for (int j = 0; j < 8; ++j) aw[tt][K][j] = (_Float16)p[j];
    }
  }
  __syncthreads();   // latent hs reads done; encs published

  // re-zero h buffers; compute gtmp[s][4u+g] = enc[s]@dWih[g*128+u] + biases
  for (int i = tid; i < 2 * SPB * HR; i += 512) hs[i] = (_Float16)0.f;
#pragma unroll 1
  for (int k = 0; k < 16; ++k) {
    int flat = tid + 512 * k;          // 8192 = 16 samples x 512 gate-rows
    int gs = flat >> 9, ridx = flat & 511;
    int uu = ridx >> 2, gg2 = ridx & 3;
    int row = gg2 * NH + uu;
    const float4* pw = (const float4*)(dWih + (size_t)row * NLAT);
    const float4* pe = (const float4*)(encs + gs * NLAT);
    float a = dBih[row] + dBhh[row];
#pragma unroll
    for (int r = 0; r < 16; ++r) {
      float4 wv = pw[r], ev = pe[r];
      a = fmaf(ev.x, wv.x, a); a = fmaf(ev.y, wv.y, a);
      a = fmaf(ev.z, wv.z, a); a = fmaf(ev.w, wv.w, a);
    }
    gtmp[gs * 512 + ridx] = a;
  }
  __syncthreads();
#pragma unroll
  for (int tt = 0; tt < 4; ++tt)
    bi[tt] = *(const f32x4*)(gtmp + s * 512 + 4 * (ubase + tt));
  c0 = c1 = c2 = c3 = 0.f;

  // ============================ DECODER ============================
#pragma unroll 1
  for (int t = 0; t < NT; ++t) {
    f32x4 acc[4];
    const _Float16* hb = hs + (t & 1) * (SPB * HR) + s * HR;
    {
      f16x8 bf = *(const f16x8*)(hb + 8 * kg);
#pragma unroll
      for (int tt = 0; tt < 4; ++tt) acc[tt] = mfma16(aw[tt][0], bf, bi[tt]);
    }
#pragma unroll
    for (int K = 1; K < 4; ++K) {
      f16x8 bf = *(const f16x8*)(hb + 32 * K + 8 * kg);
#pragma unroll
      for (int tt = 0; tt < 4; ++tt) acc[tt] = mfma16(aw[tt][K], bf, acc[tt]);
    }
    h4 hv;
    {
      float gi = sigmoid_f(acc[0][0]), gf = sigmoid_f(acc[0][1]);
      float gg = tanh_f(acc[0][2]),    go = sigmoid_f(acc[0][3]);
      c0 = fmaf(gf, c0, gi * gg); hv[0] = (_Float16)(go * tanh_f(c0));
    }
    {
      float gi = sigmoid_f(acc[1][0]), gf = sigmoid_f(acc[1][1]);
      float gg = tanh_f(acc[1][2]),    go = sigmoid_f(acc[1][3]);
      c1 = fmaf(gf, c1, gi * gg); hv[1] = (_Float16)(go * tanh_f(c1));
    }
    {
      float gi = sigmoid_f(acc[2][0]), gf = sigmoid_f(acc[2][1]);
      float gg = tanh_f(acc[2][2]),    go = sigmoid_f(acc[2][3]);
      c2 = fmaf(gf, c2, gi * gg); hv[2] = (_Float16)(go * tanh_f(c2));
    }
    {
      float gi = sigmoid_f(acc[3][0]), gf = sigmoid_f(acc[3][1]);
      float gg = tanh_f(acc[3][2]),    go = sigmoid_f(acc[3][3]);
      c3 = fmaf(gf, c3, gi * gg); hv[3] = (_Float16)(go * tanh_f(c3));
    }
    *(h4*)(hs + ((t + 1) & 1) * (SPB * HR) + s * HR + ubase) = hv;
    *(h4*)(hist + ((size_t)S * NT + t) * NH + ubase) = hv;   // stream to ws
    __syncthreads();
  }
}

// outD[b][t][:] = hist[b][t][:] @ dWl.T + dBl  (R6-verified structure)
__global__ __launch_bounds__(512, 1) void lstm_ae_epi(
    const _Float16* __restrict__ hist,   // [B][T][H] f16
    const float* __restrict__ dWl,       // [D_IN][H]
    const float* __restrict__ dBl,       // [D_IN]
    float* __restrict__ outD)            // [B][T][D_IN]
{
  const int tid = threadIdx.x;
  const int b   = blockIdx.x;            // sample
  const int col = tid & 31, rg = tid >> 5;
  h2 wl[64];
  const float4* p0 = (const float4*)(dWl + (size_t)col * NH);
#pragma unroll
  for (int f = 0; f < 32; ++f) {
    float4 v = p0[f];
    wl[2 * f] = pk2(v.x, v.y); wl[2 * f + 1] = pk2(v.z, v.w);
  }
  const float bo = dBl[col];
  float* op = outD + (size_t)b * (NT * NDIN);
#pragma unroll 1
  for (int i = 0; i < 32; ++i) {
    int r = rg + 16 * i;
    const float4* hp = (const float4*)(hist + ((size_t)b * NT + r) * NH);
    float sacc = 0.f;
#pragma unroll
    for (int j = 0; j < 16; ++j) {
      float4 hvv = hp[j];
      sacc = dot2(wl[4 * j + 0], bc2(hvv.x), sacc);
      sacc = dot2(wl[4 * j + 1], bc2(hvv.y), sacc);
      sacc = dot2(wl[4 * j + 2], bc2(hvv.z), sacc);
      sacc = dot2(wl[4 * j + 3], bc2(hvv.w), sacc);
    }
    op[(size_t)r * NDIN + col] = sacc + bo;
  }
}

extern "C" void kernel_launch(void* const* d_in, const int* in_sizes, int n_in,
                              void* d_out, int out_size, void* d_ws, size_t ws_size,
                              hipStream_t stream) {
  const float* x    = (const float*)d_in[0];
  const float* eWih = (const float*)d_in[1];
  const float* eWhh = (const float*)d_in[2];
  const float* eBih = (const float*)d_in[3];
  const float* eBhh = (const float*)d_in[4];
  const float* eWl  = (const float*)d_in[5];
  const float* eBl  = (const float*)d_in[6];
  const float* dWih = (const float*)d_in[7];
  const float* dWhh = (const float*)d_in[8];
  const float* dBih = (const float*)d_in[9];
  const float* dBhh = (const float*)d_in[10];
  const float* dWl  = (const float*)d_in[11];
  const float* dBl  = (const float*)d_in[12];

  float* outE = (float*)d_out;               // [256][64]
  float* outD = outE + (size_t)NB * NLAT;    // [256][512][32]
  _Float16* hist = (_Float16*)d_ws;          // [256][512][128] f16 = 33.5MB

  (void)hipFuncSetAttribute((const void*)lstm_ae_main,
                            hipFuncAttributeMaxDynamicSharedMemorySize,
                            SMEM_MAIN);

  hipLaunchKernelGGL(lstm_ae_main, dim3(NBLK), dim3(512), SMEM_MAIN, stream,
                     x, eWih, eWhh, eBih, eBhh, eWl, eBl,
                     dWih, dWhh, dBih, dBhh, hist, outE);
  hipLaunchKernelGGL(lstm_ae_epi, dim3(NB), dim3(512), 0, stream,
                     hist, dWl, dBl, outD);
}